// Round 6
// baseline (214.532 us; speedup 1.0000x reference)
//
#include <hip/hip_runtime.h>

#define N_NODES 100000
#define N_EDGES 1200000
#define DIM 64
#define NPW 8          // nodes per wave in aggregate
#define WPB 4          // waves per block

// ---------- CSR build ----------
// Edge kernels at 2 edges/thread: 2344 blocks = ~8 blocks/CU = full 32-wave
// residency (was 586 blocks = 9 waves/CU -> latency-bound atomics).

__global__ __launch_bounds__(256, 8) void hist_rank_kernel(
    const int* __restrict__ dst, int* __restrict__ counts,
    int* __restrict__ rank, int n2)
{
    int i = blockIdx.x * blockDim.x + threadIdx.x;
    if (i >= n2) return;
    int2 d = ((const int2*)dst)[i];
    int r0 = atomicAdd(&counts[d.x], 1);
    int r1 = atomicAdd(&counts[d.y], 1);
    ((int2*)rank)[i] = make_int2(r0, r1);
}

// Block-local scan + atomic block base (bucket order need not be node order).
__global__ __launch_bounds__(256) void offsets_kernel(
    const int* __restrict__ counts, int* __restrict__ offsets,
    int* __restrict__ base_counter, int n)
{
    __shared__ int tmp[256];
    __shared__ int base;
    int i = blockIdx.x * 256 + threadIdx.x;
    int v = (i < n) ? counts[i] : 0;
    tmp[threadIdx.x] = v;
    __syncthreads();
    #pragma unroll
    for (int d = 1; d < 256; d <<= 1) {
        int t = (threadIdx.x >= d) ? tmp[threadIdx.x - d] : 0;
        __syncthreads();
        tmp[threadIdx.x] += t;
        __syncthreads();
    }
    if (threadIdx.x == 255) base = atomicAdd(base_counter, tmp[255]);
    __syncthreads();
    if (i < n) offsets[i] = base + tmp[threadIdx.x] - v;
}

// Atomic-free scatter: pos = offsets[dst] + rank. 2 edges/thread.
__global__ __launch_bounds__(256, 8) void fill_kernel(
    const int* __restrict__ src, const int* __restrict__ dst,
    const int* __restrict__ rank, const int* __restrict__ offsets,
    int* __restrict__ csr_src, int n2)
{
    int i = blockIdx.x * blockDim.x + threadIdx.x;
    if (i >= n2) return;
    int2 s = ((const int2*)src)[i];
    int2 d = ((const int2*)dst)[i];
    int2 r = ((const int2*)rank)[i];
    csr_src[offsets[d.x] + r.x] = s.x;
    csr_src[offsets[d.y] + r.y] = s.y;
}

// ---------- fused pull-aggregate + linear ----------
// (FROZEN this round for clean attribution of the build delta.)
__global__ __launch_bounds__(256) void aggregate_linear_kernel(
    const float* __restrict__ x, const int* __restrict__ csr_src,
    const int* __restrict__ offsets, const int* __restrict__ counts,
    const float* __restrict__ W, const float* __restrict__ bias,
    float* __restrict__ out, int n_nodes)
{
    __shared__ float Ws[DIM][68];   // stride 68 words: b128 reads conflict-free (measured 0)
    __shared__ float hs[WPB][DIM];

    for (int i = threadIdx.x; i < DIM * DIM / 4; i += 256) {
        float4 wv = ((const float4*)W)[i];
        int o = i >> 4, fq = i & 15;
        *(float4*)&Ws[o][fq * 4] = wv;
    }
    __syncthreads();

    int w    = threadIdx.x >> 6;
    int lane = threadIdx.x & 63;
    int g    = lane >> 4;          // edge-group 0..3 within wave
    int gl   = lane & 15;          // feature-quad index
    float bl = bias[lane];

    int node0 = (blockIdx.x * WPB + w) * NPW;
    #pragma unroll 1
    for (int ni = 0; ni < NPW; ++ni) {
        int node = node0 + ni;
        if (node >= n_nodes) break;

        int off = offsets[node];
        int deg = counts[node];
        int end = off + deg;
        float4 a0 = {0.f, 0.f, 0.f, 0.f};
        float4 a1 = {0.f, 0.f, 0.f, 0.f};
        for (int k = off; k < end; k += 8) {
            int e0 = k + g, e1 = k + 4 + g;
            int s0 = csr_src[min(e0, end - 1)];
            int s1 = csr_src[min(e1, end - 1)];
            float4 v0 = *(const float4*)&x[(size_t)s0 * DIM + gl * 4];
            float4 v1 = *(const float4*)&x[(size_t)s1 * DIM + gl * 4];
            bool p0 = e0 < end, p1 = e1 < end;
            a0.x += p0 ? v0.x : 0.f;  a0.y += p0 ? v0.y : 0.f;
            a0.z += p0 ? v0.z : 0.f;  a0.w += p0 ? v0.w : 0.f;
            a1.x += p1 ? v1.x : 0.f;  a1.y += p1 ? v1.y : 0.f;
            a1.z += p1 ? v1.z : 0.f;  a1.w += p1 ? v1.w : 0.f;
        }
        a0.x += a1.x; a0.y += a1.y; a0.z += a1.z; a0.w += a1.w;
        a0.x += __shfl_xor(a0.x, 16, 64); a0.x += __shfl_xor(a0.x, 32, 64);
        a0.y += __shfl_xor(a0.y, 16, 64); a0.y += __shfl_xor(a0.y, 32, 64);
        a0.z += __shfl_xor(a0.z, 16, 64); a0.z += __shfl_xor(a0.z, 32, 64);
        a0.w += __shfl_xor(a0.w, 16, 64); a0.w += __shfl_xor(a0.w, 32, 64);

        float inv = 1.0f / fmaxf((float)deg, 1.0f);
        if (g == 0) {
            float4 h4 = {a0.x * inv, a0.y * inv, a0.z * inv, a0.w * inv};
            *(float4*)&hs[w][gl * 4] = h4;
        }
        __builtin_amdgcn_wave_barrier();

        float acc = bl;
        #pragma unroll
        for (int f0 = 0; f0 < DIM; f0 += 4) {
            float4 hv = *(const float4*)&hs[w][f0];     // uniform addr: broadcast
            float4 wv = *(const float4*)&Ws[lane][f0];  // balanced, 0 conflicts
            acc = fmaf(hv.x, wv.x, acc);
            acc = fmaf(hv.y, wv.y, acc);
            acc = fmaf(hv.z, wv.z, acc);
            acc = fmaf(hv.w, wv.w, acc);
        }
        __builtin_nontemporal_store(acc, &out[(size_t)node * DIM + lane]);
        __builtin_amdgcn_wave_barrier();
    }
}

extern "C" void kernel_launch(void* const* d_in, const int* in_sizes, int n_in,
                              void* d_out, int out_size, void* d_ws, size_t ws_size,
                              hipStream_t stream) {
    const float* x   = (const float*)d_in[0];
    const int*   src = (const int*)d_in[1];
    const int*   dst = (const int*)d_in[2];
    const float* W   = (const float*)d_in[3];
    const float* b   = (const float*)d_in[4];
    float* out = (float*)d_out;

    // workspace layout (ints)
    int* counts       = (int*)d_ws;             // [100032]
    int* base_counter = counts + 100032;        // [32]
    int* offsets      = base_counter + 32;      // [100032]
    int* rank         = offsets + 100032;       // [1200000]
    int* csr_src      = rank + N_EDGES;         // [1200000]

    hipMemsetAsync(counts, 0, (size_t)(100032 + 32) * sizeof(int), stream);

    int n2 = N_EDGES / 2;                       // 600000 exact
    int eb2 = (n2 + 255) / 256;                 // 2344 blocks (~8/CU)
    int nb = (N_NODES + 255) / 256;

    hist_rank_kernel<<<eb2, 256, 0, stream>>>(dst, counts, rank, n2);
    offsets_kernel  <<<nb, 256, 0, stream>>>(counts, offsets, base_counter, N_NODES);
    fill_kernel     <<<eb2, 256, 0, stream>>>(src, dst, rank, offsets, csr_src, n2);

    int blocks = (N_NODES + WPB * NPW - 1) / (WPB * NPW);   // 3125
    aggregate_linear_kernel<<<blocks, 256, 0, stream>>>(
        x, csr_src, offsets, counts, W, b, out, N_NODES);
}